// Round 1
// baseline (469.492 us; speedup 1.0000x reference)
//
#include <hip/hip_runtime.h>
#include <hip/hip_bf16.h>

typedef __bf16 bf16;
typedef __attribute__((ext_vector_type(8))) __bf16 bf16x8;
typedef __attribute__((ext_vector_type(4))) float floatx4;

#define MFMA16(a, b, c) __builtin_amdgcn_mfma_f32_16x16x32_bf16((a), (b), (c), 0, 0, 0)

#define DIM 384
#define T1 3136   // 56*56
#define T2 784    // 28*28
#define B_ 8
#define EPSV 1e-5f

// ---------------- depthwise conv + BN (q, stride 1) ----------------
__global__ void conv_q_kernel(const float* __restrict__ x,
                              const float* __restrict__ wc,
                              const float* __restrict__ g, const float* __restrict__ bb,
                              const float* __restrict__ mm, const float* __restrict__ vv,
                              bf16* __restrict__ out) {
  int blk = blockIdx.x;          // b*3136 + t
  int c = threadIdx.x;           // 0..383
  int t = blk % T1, b = blk / T1;
  int y = t / 56, xx = t % 56;
  const float* xb = x + (size_t)b * T1 * DIM;
  float s = 0.f;
#pragma unroll
  for (int ky = 0; ky < 3; ++ky) {
    int yy = y + ky - 1;
    if (yy < 0 || yy >= 56) continue;
#pragma unroll
    for (int kx = 0; kx < 3; ++kx) {
      int xc = xx + kx - 1;
      if (xc < 0 || xc >= 56) continue;
      s += xb[(yy * 56 + xc) * DIM + c] * wc[c * 9 + ky * 3 + kx];
    }
  }
  float a = rsqrtf(vv[c] + EPSV) * g[c];
  out[(size_t)blk * DIM + c] = (bf16)((s - mm[c]) * a + bb[c]);
}

// ---------------- depthwise conv + BN (k and v fused, stride 2) ----------------
__global__ void conv_kv_kernel(const float* __restrict__ x,
    const float* __restrict__ wkc, const float* __restrict__ gk, const float* __restrict__ bk,
    const float* __restrict__ mk, const float* __restrict__ vk,
    const float* __restrict__ wvc, const float* __restrict__ gv, const float* __restrict__ bv,
    const float* __restrict__ mv, const float* __restrict__ vvv,
    bf16* __restrict__ kout, bf16* __restrict__ vout) {
  int blk = blockIdx.x;          // b*784 + t2
  int c = threadIdx.x;
  int t2 = blk % T2, b = blk / T2;
  int y2 = t2 / 28, x2 = t2 % 28;
  const float* xb = x + (size_t)b * T1 * DIM;
  float sk = 0.f, sv = 0.f;
#pragma unroll
  for (int ky = 0; ky < 3; ++ky) {
    int yy = 2 * y2 + ky - 1;
    if (yy < 0 || yy >= 56) continue;
#pragma unroll
    for (int kx = 0; kx < 3; ++kx) {
      int xc = 2 * x2 + kx - 1;
      if (xc < 0 || xc >= 56) continue;
      float xv = xb[(yy * 56 + xc) * DIM + c];
      sk += xv * wkc[c * 9 + ky * 3 + kx];
      sv += xv * wvc[c * 9 + ky * 3 + kx];
    }
  }
  float ak = rsqrtf(vk[c] + EPSV) * gk[c];
  float av = rsqrtf(vvv[c] + EPSV) * gv[c];
  kout[(size_t)blk * DIM + c] = (bf16)((sk - mk[c]) * ak + bk[c]);
  vout[(size_t)blk * DIM + c] = (bf16)((sv - mv[c]) * av + bv[c]);
}

// ---------------- fp32 -> bf16 weight conversion (4 matrices of 384x384) ----------------
__global__ void cvt4_kernel(const float* __restrict__ s0, const float* __restrict__ s1,
                            const float* __restrict__ s2, const float* __restrict__ s3,
                            bf16* __restrict__ d0, bf16* __restrict__ d1,
                            bf16* __restrict__ d2, bf16* __restrict__ d3) {
  int i = blockIdx.x * 256 + threadIdx.x;   // grid sized to exactly 384*384
  d0[i] = (bf16)s0[i];
  d1[i] = (bf16)s1[i];
  d2[i] = (bf16)s2[i];
  d3[i] = (bf16)s3[i];
}

// ---------------- bf16 GEMM: C[M,384] = A[M,384] @ W[384,384]^T ----------------
// A row-major [M][K], W row-major [N][K] (torch Linear weight). 128x128 tile, BK=32.
// modes: 0 = bf16 out (scale applied), 1 = same (Q, scale=SCALE), 2 = transposed bf16
// out Vt[b][n][t] (row = b*784+t), 3 = fp32 out + bias.
#define GLDS 56   // padded LDS row stride in shorts (112B: 16B-aligned, 2-way bank alias)
__global__ __launch_bounds__(256)
void gemm_bf16_kernel(const bf16* __restrict__ A, const bf16* __restrict__ Bw,
                      void* __restrict__ out, const float* __restrict__ bias,
                      int M, int mode, float scale) {
  __shared__ bf16 Al[128 * GLDS];
  __shared__ bf16 Bl[128 * GLDS];
  int tid = threadIdx.x;
  int m0 = blockIdx.x * 128, n0 = blockIdx.y * 128;
  int w = tid >> 6, lane = tid & 63;
  int wm = w >> 1, wn = w & 1;
  int l16 = lane & 15, quad = lane >> 4;
  floatx4 acc[4][4];
#pragma unroll
  for (int i = 0; i < 4; ++i)
#pragma unroll
    for (int j = 0; j < 4; ++j) acc[i][j] = (floatx4){0.f, 0.f, 0.f, 0.f};

  int r = tid >> 2;              // 0..63
  int kc = (tid & 3) * 8;        // 0,8,16,24
  for (int k0 = 0; k0 < DIM; k0 += 32) {
    __syncthreads();
#pragma unroll
    for (int p = 0; p < 2; ++p) {
      int row = r + p * 64;
      *(bf16x8*)&Al[row * GLDS + kc] = *(const bf16x8*)&A[(size_t)(m0 + row) * DIM + k0 + kc];
      *(bf16x8*)&Bl[row * GLDS + kc] = *(const bf16x8*)&Bw[(size_t)(n0 + row) * DIM + k0 + kc];
    }
    __syncthreads();
    bf16x8 af[4], bfr[4];
#pragma unroll
    for (int i = 0; i < 4; ++i) {
      af[i]  = *(const bf16x8*)&Al[(wm * 64 + i * 16 + l16) * GLDS + quad * 8];
      bfr[i] = *(const bf16x8*)&Bl[(wn * 64 + i * 16 + l16) * GLDS + quad * 8];
    }
#pragma unroll
    for (int i = 0; i < 4; ++i)
#pragma unroll
      for (int j = 0; j < 4; ++j)
        acc[i][j] = MFMA16(af[i], bfr[j], acc[i][j]);
  }
  // epilogue: C/D layout col = lane&15, row = quad*4 + reg
#pragma unroll
  for (int i = 0; i < 4; ++i) {
#pragma unroll
    for (int j = 0; j < 4; ++j) {
#pragma unroll
      for (int rr = 0; rr < 4; ++rr) {
        int row = m0 + wm * 64 + i * 16 + quad * 4 + rr;
        int col = n0 + wn * 64 + j * 16 + l16;
        float v = acc[i][j][rr];
        if (mode == 3) {
          ((float*)out)[(size_t)row * DIM + col] = v + bias[col];
        } else if (mode == 2) {
          int b = row / T2;
          int t = row - b * T2;
          ((bf16*)out)[((size_t)b * DIM + col) * T2 + t] = (bf16)v;
        } else {
          ((bf16*)out)[(size_t)row * DIM + col] = (bf16)(v * scale);
        }
      }
    }
  }
}

// ---------------- flash attention ----------------
// block = 256 thr = 4 waves; one (b,h), 64 q-rows (16 per wave); KV tiles of 64, 13 iters.
// Qp pre-scaled by SCALE. Kp [B*784][384]. Vt [B][384][784] (transposed).
#define ALDS 72   // padded LDS row stride in shorts (144B)
__global__ __launch_bounds__(256)
void attn_kernel(const bf16* __restrict__ Qp, const bf16* __restrict__ Kp,
                 const bf16* __restrict__ Vt, bf16* __restrict__ Ob) {
  __shared__ bf16 Kl[64 * ALDS];
  __shared__ bf16 Vl[64 * ALDS];
  __shared__ bf16 Pl[4][16 * ALDS];
  int blk = blockIdx.x;
  int qt = blk % 49;
  int h = (blk / 49) % 6;
  int b = blk / (49 * 6);
  int tid = threadIdx.x, w = tid >> 6, lane = tid & 63;
  int l16 = lane & 15, quad = lane >> 4;
  int q0 = qt * 64 + w * 16;     // q row base within this b (wave-local)

  // Q fragments (A-layout: m = lane&15, k = quad*8+j), stay in regs all kernel
  bf16x8 qf[2];
  {
    size_t qrow = (size_t)(b * T1 + q0 + l16) * DIM + h * 64;
    qf[0] = *(const bf16x8*)&Qp[qrow + quad * 8];
    qf[1] = *(const bf16x8*)&Qp[qrow + 32 + quad * 8];
  }
  floatx4 oacc[4];
#pragma unroll
  for (int j = 0; j < 4; ++j) oacc[j] = (floatx4){0.f, 0.f, 0.f, 0.f};
  float mrow[4], lrow[4];
#pragma unroll
  for (int rr = 0; rr < 4; ++rr) { mrow[rr] = -1e30f; lrow[rr] = 0.f; }

  int sr = tid >> 3;             // 0..31
  int sc = (tid & 7) * 8;        // 0..56

  for (int kv0 = 0; kv0 < 832; kv0 += 64) {
    __syncthreads();
    // stage K tile [t 0..63][d 0..63] and V^T tile [d 0..63][t 0..63]
#pragma unroll
    for (int p = 0; p < 2; ++p) {
      int row = sr + p * 32;
      int tg = kv0 + row;
      if (tg < T2)
        *(bf16x8*)&Kl[row * ALDS + sc] =
            *(const bf16x8*)&Kp[(size_t)(b * T2 + tg) * DIM + h * 64 + sc];
      int tcol = kv0 + sc;
      if (tcol < T2)
        *(bf16x8*)&Vl[row * ALDS + sc] =
            *(const bf16x8*)&Vt[((size_t)b * DIM + h * 64 + row) * T2 + tcol];
    }
    __syncthreads();
    // S = Q K^T  (4 n-tiles of 16 t's, K=64 via 2 mfma)
    floatx4 s[4];
#pragma unroll
    for (int nt = 0; nt < 4; ++nt) {
      bf16x8 kf0 = *(const bf16x8*)&Kl[(nt * 16 + l16) * ALDS + quad * 8];
      bf16x8 kf1 = *(const bf16x8*)&Kl[(nt * 16 + l16) * ALDS + 32 + quad * 8];
      floatx4 z = (floatx4){0.f, 0.f, 0.f, 0.f};
      z = MFMA16(qf[0], kf0, z);
      z = MFMA16(qf[1], kf1, z);
      s[nt] = z;
    }
    // mask t >= 784
#pragma unroll
    for (int nt = 0; nt < 4; ++nt) {
      int tg = kv0 + nt * 16 + l16;
      if (tg >= T2) s[nt] = (floatx4){-1e30f, -1e30f, -1e30f, -1e30f};
    }
    // online softmax (rows live in the 16-lane quad, 4 rows per lane as regs)
    float mnew[4], alpha[4];
#pragma unroll
    for (int rr = 0; rr < 4; ++rr) {
      float mx = fmaxf(fmaxf(s[0][rr], s[1][rr]), fmaxf(s[2][rr], s[3][rr]));
      mx = fmaxf(mx, __shfl_xor(mx, 1));
      mx = fmaxf(mx, __shfl_xor(mx, 2));
      mx = fmaxf(mx, __shfl_xor(mx, 4));
      mx = fmaxf(mx, __shfl_xor(mx, 8));
      mnew[rr] = fmaxf(mrow[rr], mx);
      alpha[rr] = __expf(mrow[rr] - mnew[rr]);
      mrow[rr] = mnew[rr];
    }
#pragma unroll
    for (int rr = 0; rr < 4; ++rr) {
      float ls = 0.f;
#pragma unroll
      for (int nt = 0; nt < 4; ++nt) {
        float p = __expf(s[nt][rr] - mnew[rr]);
        s[nt][rr] = p;
        ls += p;
      }
      ls += __shfl_xor(ls, 1);
      ls += __shfl_xor(ls, 2);
      ls += __shfl_xor(ls, 4);
      ls += __shfl_xor(ls, 8);
      lrow[rr] = lrow[rr] * alpha[rr] + ls;
#pragma unroll
      for (int j = 0; j < 4; ++j) oacc[j][rr] *= alpha[rr];
    }
    // P: C-layout -> LDS (per-wave region) for A-layout reads
#pragma unroll
    for (int nt = 0; nt < 4; ++nt)
#pragma unroll
      for (int rr = 0; rr < 4; ++rr)
        Pl[w][(quad * 4 + rr) * ALDS + nt * 16 + l16] = (bf16)s[nt][rr];
    __syncthreads();
    // O += P V
#pragma unroll
    for (int kt = 0; kt < 2; ++kt) {
      bf16x8 pf = *(const bf16x8*)&Pl[w][l16 * ALDS + kt * 32 + quad * 8];
#pragma unroll
      for (int dt = 0; dt < 4; ++dt) {
        bf16x8 vf = *(const bf16x8*)&Vl[(dt * 16 + l16) * ALDS + kt * 32 + quad * 8];
        oacc[dt] = MFMA16(pf, vf, oacc[dt]);
      }
    }
  }
  // epilogue: divide by l, write o[b*T1+row][h*64+col] bf16
#pragma unroll
  for (int rr = 0; rr < 4; ++rr) {
    float inv = 1.f / lrow[rr];
    size_t orow = (size_t)(b * T1 + q0 + quad * 4 + rr) * DIM + h * 64;
#pragma unroll
    for (int dt = 0; dt < 4; ++dt)
      Ob[orow + dt * 16 + l16] = (bf16)(oacc[dt][rr] * inv);
  }
}

// ---------------- launch ----------------
extern "C" void kernel_launch(void* const* d_in, const int* in_sizes, int n_in,
                              void* d_out, int out_size, void* d_ws, size_t ws_size,
                              hipStream_t stream) {
  (void)in_sizes; (void)n_in; (void)out_size; (void)ws_size;
  const float* x      = (const float*)d_in[0];
  const float* conv_q = (const float*)d_in[3];
  const float* bnq_s  = (const float*)d_in[4];
  const float* bnq_b  = (const float*)d_in[5];
  const float* bnq_m  = (const float*)d_in[6];
  const float* bnq_v  = (const float*)d_in[7];
  const float* conv_k = (const float*)d_in[8];
  const float* bnk_s  = (const float*)d_in[9];
  const float* bnk_b  = (const float*)d_in[10];
  const float* bnk_m  = (const float*)d_in[11];
  const float* bnk_v  = (const float*)d_in[12];
  const float* conv_v = (const float*)d_in[13];
  const float* bnv_s  = (const float*)d_in[14];
  const float* bnv_b  = (const float*)d_in[15];
  const float* bnv_m  = (const float*)d_in[16];
  const float* bnv_v  = (const float*)d_in[17];
  const float* wq     = (const float*)d_in[18];
  const float* wk     = (const float*)d_in[19];
  const float* wv     = (const float*)d_in[20];
  const float* wl     = (const float*)d_in[21];
  const float* b_last = (const float*)d_in[22];

  char* ws = (char*)d_ws;
  // q_act region is reused as the attention output buffer (q_act dead after Q GEMM)
  bf16* q_act = (bf16*)(ws + 0);               // 25088*384*2 = 19267584
  bf16* k_act = (bf16*)(ws + 19267584);        //  6272*384*2 =  4816896
  bf16* v_act = (bf16*)(ws + 24084480);        //  4816896
  bf16* Qp    = (bf16*)(ws + 28901376);        // 19267584 (pre-scaled by SCALE)
  bf16* Kp    = (bf16*)(ws + 48168960);        //  4816896
  bf16* Vtp   = (bf16*)(ws + 52985856);        //  4816896  [B][384][784]
  bf16* wqb   = (bf16*)(ws + 57802752);        // 294912 each, x4
  bf16* wkb   = wqb + 147456;
  bf16* wvb   = wkb + 147456;
  bf16* wlb   = wvb + 147456;

  const float SCALE = 0.05103103630798288f;    // 384^-0.5

  conv_q_kernel<<<B_ * T1, DIM, 0, stream>>>(x, conv_q, bnq_s, bnq_b, bnq_m, bnq_v, q_act);
  conv_kv_kernel<<<B_ * T2, DIM, 0, stream>>>(x, conv_k, bnk_s, bnk_b, bnk_m, bnk_v,
                                              conv_v, bnv_s, bnv_b, bnv_m, bnv_v,
                                              k_act, v_act);
  cvt4_kernel<<<576, 256, 0, stream>>>(wq, wk, wv, wl, wqb, wkb, wvb, wlb);

  gemm_bf16_kernel<<<dim3(196, 3), 256, 0, stream>>>(q_act, wqb, Qp, nullptr,
                                                     B_ * T1, 1, SCALE);
  gemm_bf16_kernel<<<dim3(49, 3), 256, 0, stream>>>(k_act, wkb, Kp, nullptr,
                                                    B_ * T2, 0, 1.f);
  gemm_bf16_kernel<<<dim3(49, 3), 256, 0, stream>>>(v_act, wvb, Vtp, nullptr,
                                                    B_ * T2, 2, 1.f);

  attn_kernel<<<B_ * 6 * 49, 256, 0, stream>>>(Qp, Kp, Vtp, q_act);

  gemm_bf16_kernel<<<dim3(196, 3), 256, 0, stream>>>(q_act, wlb, d_out, b_last,
                                                     B_ * T1, 3, 1.f);
}

// Round 2
// 356.617 us; speedup vs baseline: 1.3165x; 1.3165x over previous
//
#include <hip/hip_runtime.h>
#include <hip/hip_bf16.h>

typedef __bf16 bf16;
typedef __attribute__((ext_vector_type(8))) __bf16 bf16x8;
typedef __attribute__((ext_vector_type(4))) __bf16 bf16x4;
typedef __attribute__((ext_vector_type(4))) float floatx4;

#define MFMA16(a, b, c) __builtin_amdgcn_mfma_f32_16x16x32_bf16((a), (b), (c), 0, 0, 0)

#define DIM 384
#define T1 3136   // 56*56
#define T2 784    // 28*28
#define B_ 8
#define EPSV 1e-5f

// ---------------- depthwise conv + BN (q, stride 1), 4-wide x tiling ----------------
__global__ void conv_q_kernel(const float* __restrict__ x,
                              const float* __restrict__ wc,
                              const float* __restrict__ g, const float* __restrict__ bb,
                              const float* __restrict__ mm, const float* __restrict__ vv,
                              bf16* __restrict__ out) {
  int blk = blockIdx.x;          // xg + 14*(y + 56*b)
  int c = threadIdx.x;           // 0..383
  int xg = blk % 14;
  int y = (blk / 14) % 56;
  int b = blk / (14 * 56);
  int x0 = xg * 4;
  const float* xb = x + (size_t)b * T1 * DIM;
  float wr[9];
#pragma unroll
  for (int i = 0; i < 9; ++i) wr[i] = wc[c * 9 + i];
  float a = rsqrtf(vv[c] + EPSV) * g[c];
  float bia = bb[c] - mm[c] * a;
  float in[3][6];
#pragma unroll
  for (int r = 0; r < 3; ++r) {
    int yy = y + r - 1;
#pragma unroll
    for (int cc = 0; cc < 6; ++cc) {
      int xc = x0 + cc - 1;
      in[r][cc] = (yy >= 0 && yy < 56 && xc >= 0 && xc < 56)
                      ? xb[(yy * 56 + xc) * DIM + c] : 0.f;
    }
  }
#pragma unroll
  for (int p = 0; p < 4; ++p) {
    float s = 0.f;
#pragma unroll
    for (int r = 0; r < 3; ++r)
#pragma unroll
      for (int dx = 0; dx < 3; ++dx) s += in[r][p + dx] * wr[r * 3 + dx];
    out[((size_t)b * T1 + y * 56 + x0 + p) * DIM + c] = (bf16)(s * a + bia);
  }
}

// ---------------- depthwise conv + BN (k and v fused, stride 2), 4-wide ----------------
__global__ void conv_kv_kernel(const float* __restrict__ x,
    const float* __restrict__ wkc, const float* __restrict__ gk, const float* __restrict__ bk,
    const float* __restrict__ mk, const float* __restrict__ vk,
    const float* __restrict__ wvc, const float* __restrict__ gv, const float* __restrict__ bv,
    const float* __restrict__ mv, const float* __restrict__ vvv,
    bf16* __restrict__ kout, bf16* __restrict__ vout) {
  int blk = blockIdx.x;          // xg + 7*(y2 + 28*b)
  int c = threadIdx.x;
  int xg = blk % 7;
  int y2 = (blk / 7) % 28;
  int b = blk / (7 * 28);
  int x20 = xg * 4;
  const float* xb = x + (size_t)b * T1 * DIM;
  float wk9[9], wv9[9];
#pragma unroll
  for (int i = 0; i < 9; ++i) { wk9[i] = wkc[c * 9 + i]; wv9[i] = wvc[c * 9 + i]; }
  float ak = rsqrtf(vk[c] + EPSV) * gk[c];
  float av = rsqrtf(vvv[c] + EPSV) * gv[c];
  float bik = bk[c] - mk[c] * ak;
  float biv = bv[c] - mv[c] * av;
  float in[3][9];
  int y = 2 * y2;
#pragma unroll
  for (int r = 0; r < 3; ++r) {
    int yy = y + r - 1;
#pragma unroll
    for (int cc = 0; cc < 9; ++cc) {
      int xc = 2 * x20 + cc - 1;
      in[r][cc] = (yy >= 0 && yy < 56 && xc >= 0 && xc < 56)
                      ? xb[(yy * 56 + xc) * DIM + c] : 0.f;
    }
  }
#pragma unroll
  for (int p = 0; p < 4; ++p) {
    float sk = 0.f, sv = 0.f;
#pragma unroll
    for (int r = 0; r < 3; ++r)
#pragma unroll
      for (int dx = 0; dx < 3; ++dx) {
        float xv = in[r][2 * p + dx];
        sk += xv * wk9[r * 3 + dx];
        sv += xv * wv9[r * 3 + dx];
      }
    size_t o = ((size_t)b * T2 + y2 * 28 + x20 + p) * DIM + c;
    kout[o] = (bf16)(sk * ak + bik);
    vout[o] = (bf16)(sv * av + biv);
  }
}

// ---------------- fp32 -> bf16 weight conversion (4 matrices of 384x384) ----------------
__global__ void cvt4_kernel(const float* __restrict__ s0, const float* __restrict__ s1,
                            const float* __restrict__ s2, const float* __restrict__ s3,
                            bf16* __restrict__ d0, bf16* __restrict__ d1,
                            bf16* __restrict__ d2, bf16* __restrict__ d3) {
  int i = blockIdx.x * 256 + threadIdx.x;   // grid sized to exactly 384*384
  d0[i] = (bf16)s0[i];
  d1[i] = (bf16)s1[i];
  d2[i] = (bf16)s2[i];
  d3[i] = (bf16)s3[i];
}

// ---------------- bf16 GEMM: C[M,384] = A[M,384] @ W[384,384]^T ----------------
#define GLDS 56
__global__ __launch_bounds__(256)
void gemm_bf16_kernel(const bf16* __restrict__ A, const bf16* __restrict__ Bw,
                      void* __restrict__ out, const float* __restrict__ bias,
                      int M, int mode, float scale) {
  __shared__ bf16 Al[128 * GLDS];
  __shared__ bf16 Bl[128 * GLDS];
  int tid = threadIdx.x;
  int m0 = blockIdx.x * 128, n0 = blockIdx.y * 128;
  int w = tid >> 6, lane = tid & 63;
  int wm = w >> 1, wn = w & 1;
  int l16 = lane & 15, quad = lane >> 4;
  floatx4 acc[4][4];
#pragma unroll
  for (int i = 0; i < 4; ++i)
#pragma unroll
    for (int j = 0; j < 4; ++j) acc[i][j] = (floatx4){0.f, 0.f, 0.f, 0.f};

  int r = tid >> 2;
  int kc = (tid & 3) * 8;
  for (int k0 = 0; k0 < DIM; k0 += 32) {
    __syncthreads();
#pragma unroll
    for (int p = 0; p < 2; ++p) {
      int row = r + p * 64;
      *(bf16x8*)&Al[row * GLDS + kc] = *(const bf16x8*)&A[(size_t)(m0 + row) * DIM + k0 + kc];
      *(bf16x8*)&Bl[row * GLDS + kc] = *(const bf16x8*)&Bw[(size_t)(n0 + row) * DIM + k0 + kc];
    }
    __syncthreads();
    bf16x8 af[4], bfr[4];
#pragma unroll
    for (int i = 0; i < 4; ++i) {
      af[i]  = *(const bf16x8*)&Al[(wm * 64 + i * 16 + l16) * GLDS + quad * 8];
      bfr[i] = *(const bf16x8*)&Bl[(wn * 64 + i * 16 + l16) * GLDS + quad * 8];
    }
#pragma unroll
    for (int i = 0; i < 4; ++i)
#pragma unroll
      for (int j = 0; j < 4; ++j)
        acc[i][j] = MFMA16(af[i], bfr[j], acc[i][j]);
  }
#pragma unroll
  for (int i = 0; i < 4; ++i) {
#pragma unroll
    for (int j = 0; j < 4; ++j) {
#pragma unroll
      for (int rr = 0; rr < 4; ++rr) {
        int row = m0 + wm * 64 + i * 16 + quad * 4 + rr;
        int col = n0 + wn * 64 + j * 16 + l16;
        float v = acc[i][j][rr];
        if (mode == 3) {
          ((float*)out)[(size_t)row * DIM + col] = v + bias[col];
        } else if (mode == 2) {
          int b = row / T2;
          int t = row - b * T2;
          ((bf16*)out)[((size_t)b * DIM + col) * T2 + t] = (bf16)v;
        } else {
          ((bf16*)out)[(size_t)row * DIM + col] = (bf16)(v * scale);
        }
      }
    }
  }
}

// ---------------- flash attention, S^T/O^T form, no-max softmax ----------------
// Block = 4 waves; wave handles 32 q-rows (2 q-tiles of 16); block = 128 q of one (b,h).
// KV tiles of 64, 13 iters. Qp pre-scaled by SCALE*log2(e); p = exp2(s).
// S^T = MFMA(kf, qf): lane's S elems all at q = lane&15 -> scalar per-lane l partials,
// P write is ds_write_b64, P is wave-private (no barrier), O^T = MFMA(vf, pf).
#define ALDS 72   // LDS row stride in shorts (144 B; 36 dwords == 4 mod 32 banks)
__global__ __launch_bounds__(256)
void attn_kernel(const bf16* __restrict__ Qp, const bf16* __restrict__ Kp,
                 const bf16* __restrict__ Vt, bf16* __restrict__ Ob) {
  __shared__ bf16 Kl[64 * ALDS];          // [t][d]
  __shared__ bf16 Vl[64 * ALDS];          // [d][t]
  __shared__ bf16 Pl[4][2][16 * ALDS];    // per-wave, per-qtile [q][t]
  int blk = blockIdx.x;
  int qblk = blk % 25;
  int h = (blk / 25) % 6;
  int b = blk / (25 * 6);
  int tid = threadIdx.x, w = tid >> 6, lane = tid & 63;
  int l16 = lane & 15, quad = lane >> 4;
  int q0w = qblk * 128 + w * 32;          // wave's q base within this b

  // Q fragments (B-operand layout: n = lane&15, k = quad*8+j); clamp OOB rows
  bf16x8 qf[2][2];
#pragma unroll
  for (int qt = 0; qt < 2; ++qt) {
    int qi = q0w + qt * 16 + l16;
    qi = qi < T1 ? qi : T1 - 1;
    const bf16* qp = &Qp[((size_t)b * T1 + qi) * DIM + h * 64];
    qf[qt][0] = *(const bf16x8*)&qp[quad * 8];
    qf[qt][1] = *(const bf16x8*)&qp[32 + quad * 8];
  }
  floatx4 oacc[2][4];
#pragma unroll
  for (int qt = 0; qt < 2; ++qt)
#pragma unroll
    for (int dt = 0; dt < 4; ++dt) oacc[qt][dt] = (floatx4){0.f, 0.f, 0.f, 0.f};
  float lsum[2] = {0.f, 0.f};

  int r4 = tid >> 2;             // 0..63
  int c4 = tid & 3;              // 0..3

  for (int kv0 = 0; kv0 < 832; kv0 += 64) {
    __syncthreads();
    // stage K [t][d] rows and V^T [d][t] rows
    if (kv0 + r4 < T2) {
      const bf16* kg = &Kp[((size_t)b * T2 + kv0 + r4) * DIM + h * 64 + c4 * 16];
      *(bf16x8*)&Kl[r4 * ALDS + c4 * 16] = *(const bf16x8*)&kg[0];
      *(bf16x8*)&Kl[r4 * ALDS + c4 * 16 + 8] = *(const bf16x8*)&kg[8];
    }
    {
      const bf16* vg = &Vt[((size_t)b * DIM + h * 64 + r4) * T2 + kv0 + c4 * 16];
      if (kv0 + c4 * 16 + 8 <= T2)
        *(bf16x8*)&Vl[r4 * ALDS + c4 * 16] = *(const bf16x8*)&vg[0];
      if (kv0 + c4 * 16 + 16 <= T2)
        *(bf16x8*)&Vl[r4 * ALDS + c4 * 16 + 8] = *(const bf16x8*)&vg[8];
    }
    __syncthreads();

    int mtmax = (kv0 + 64 <= T2) ? 4 : 1;   // last tile: only first 16 t valid
#pragma unroll
    for (int mt = 0; mt < 4; ++mt) {
      bf16x8 kf0, kf1;
      if (mt < mtmax) {
        kf0 = *(const bf16x8*)&Kl[(mt * 16 + l16) * ALDS + quad * 8];
        kf1 = *(const bf16x8*)&Kl[(mt * 16 + l16) * ALDS + 32 + quad * 8];
      }
#pragma unroll
      for (int qt = 0; qt < 2; ++qt) {
        bf16x4 pw;
        if (mt < mtmax) {
          floatx4 z = (floatx4){0.f, 0.f, 0.f, 0.f};
          z = MFMA16(kf0, qf[qt][0], z);
          z = MFMA16(kf1, qf[qt][1], z);
          float p0 = __builtin_amdgcn_exp2f(z[0]);
          float p1 = __builtin_amdgcn_exp2f(z[1]);
          float p2 = __builtin_amdgcn_exp2f(z[2]);
          float p3 = __builtin_amdgcn_exp2f(z[3]);
          lsum[qt] += (p0 + p1) + (p2 + p3);
          pw = (bf16x4){(bf16)p0, (bf16)p1, (bf16)p2, (bf16)p3};
        } else {
          pw = (bf16x4){(bf16)0.f, (bf16)0.f, (bf16)0.f, (bf16)0.f};
        }
        *(bf16x4*)&Pl[w][qt][l16 * ALDS + mt * 16 + quad * 4] = pw;
      }
    }
    // O^T += V^T P^T  (wave-private P: same-wave DS ordering, no barrier)
#pragma unroll
    for (int kt = 0; kt < 2; ++kt) {
      bf16x8 pf0 = *(const bf16x8*)&Pl[w][0][l16 * ALDS + kt * 32 + quad * 8];
      bf16x8 pf1 = *(const bf16x8*)&Pl[w][1][l16 * ALDS + kt * 32 + quad * 8];
#pragma unroll
      for (int dt = 0; dt < 4; ++dt) {
        bf16x8 vf = *(const bf16x8*)&Vl[(dt * 16 + l16) * ALDS + kt * 32 + quad * 8];
        oacc[0][dt] = MFMA16(vf, pf0, oacc[0][dt]);
        oacc[1][dt] = MFMA16(vf, pf1, oacc[1][dt]);
      }
    }
  }
  // epilogue: reduce l across quads (2 shuffles), scale, pack 4 bf16 -> 8B stores
#pragma unroll
  for (int qt = 0; qt < 2; ++qt) {
    float l = lsum[qt];
    l += __shfl_xor(l, 16);
    l += __shfl_xor(l, 32);
    float inv = 1.f / l;
    int qg = q0w + qt * 16 + l16;
    if (qg < T1) {
      bf16* op = &Ob[((size_t)b * T1 + qg) * DIM + h * 64];
#pragma unroll
      for (int dt = 0; dt < 4; ++dt) {
        floatx4 o = oacc[qt][dt];
        bf16x4 ov = (bf16x4){(bf16)(o[0] * inv), (bf16)(o[1] * inv),
                             (bf16)(o[2] * inv), (bf16)(o[3] * inv)};
        *(bf16x4*)&op[dt * 16 + quad * 4] = ov;
      }
    }
  }
}

// ---------------- launch ----------------
extern "C" void kernel_launch(void* const* d_in, const int* in_sizes, int n_in,
                              void* d_out, int out_size, void* d_ws, size_t ws_size,
                              hipStream_t stream) {
  (void)in_sizes; (void)n_in; (void)out_size; (void)ws_size;
  const float* x      = (const float*)d_in[0];
  const float* conv_q = (const float*)d_in[3];
  const float* bnq_s  = (const float*)d_in[4];
  const float* bnq_b  = (const float*)d_in[5];
  const float* bnq_m  = (const float*)d_in[6];
  const float* bnq_v  = (const float*)d_in[7];
  const float* conv_k = (const float*)d_in[8];
  const float* bnk_s  = (const float*)d_in[9];
  const float* bnk_b  = (const float*)d_in[10];
  const float* bnk_m  = (const float*)d_in[11];
  const float* bnk_v  = (const float*)d_in[12];
  const float* conv_v = (const float*)d_in[13];
  const float* bnv_s  = (const float*)d_in[14];
  const float* bnv_b  = (const float*)d_in[15];
  const float* bnv_m  = (const float*)d_in[16];
  const float* bnv_v  = (const float*)d_in[17];
  const float* wq     = (const float*)d_in[18];
  const float* wk     = (const float*)d_in[19];
  const float* wv     = (const float*)d_in[20];
  const float* wl     = (const float*)d_in[21];
  const float* b_last = (const float*)d_in[22];

  char* ws = (char*)d_ws;
  bf16* q_act = (bf16*)(ws + 0);               // reused as attention output
  bf16* k_act = (bf16*)(ws + 19267584);
  bf16* v_act = (bf16*)(ws + 24084480);
  bf16* Qp    = (bf16*)(ws + 28901376);        // pre-scaled by SCALE*log2e
  bf16* Kp    = (bf16*)(ws + 48168960);
  bf16* Vtp   = (bf16*)(ws + 52985856);        // [B][384][784]
  bf16* wqb   = (bf16*)(ws + 57802752);
  bf16* wkb   = wqb + 147456;
  bf16* wvb   = wkb + 147456;
  bf16* wlb   = wvb + 147456;

  const float QSCALE = 0.05103103630798288f * 1.4426950408889634f;  // 384^-0.5 * log2(e)

  conv_q_kernel<<<B_ * 56 * 14, DIM, 0, stream>>>(x, conv_q, bnq_s, bnq_b, bnq_m, bnq_v, q_act);
  conv_kv_kernel<<<B_ * 28 * 7, DIM, 0, stream>>>(x, conv_k, bnk_s, bnk_b, bnk_m, bnk_v,
                                                  conv_v, bnv_s, bnv_b, bnv_m, bnv_v,
                                                  k_act, v_act);
  cvt4_kernel<<<576, 256, 0, stream>>>(wq, wk, wv, wl, wqb, wkb, wvb, wlb);

  gemm_bf16_kernel<<<dim3(196, 3), 256, 0, stream>>>(q_act, wqb, Qp, nullptr,
                                                     B_ * T1, 1, QSCALE);
  gemm_bf16_kernel<<<dim3(49, 3), 256, 0, stream>>>(k_act, wkb, Kp, nullptr,
                                                    B_ * T2, 0, 1.f);
  gemm_bf16_kernel<<<dim3(49, 3), 256, 0, stream>>>(v_act, wvb, Vtp, nullptr,
                                                    B_ * T2, 2, 1.f);

  attn_kernel<<<25 * 6 * B_, 256, 0, stream>>>(Qp, Kp, Vtp, q_act);

  gemm_bf16_kernel<<<dim3(196, 3), 256, 0, stream>>>(q_act, wlb, d_out, b_last,
                                                     B_ * T1, 3, 1.f);
}